// Round 1
// baseline (1642.590 us; speedup 1.0000x reference)
//
#include <hip/hip_runtime.h>
#include <hip/hip_bf16.h>
#include <math.h>

// TriangleAttention, B=1, N=256, IN_DIM=128, H=4, D=32.
// Round 1: correctness-first f32 pipeline, 3 kernels.
// ws layout (floats):
//   qkv : [65536][384]   (q = [..][h*32+d], k = +128, v = +256)
//   pb  : [65536][4]     (position = i*256+j)
//   gate: [65536][128]
//   ao  : [65536][128]   (attention output, pre-gate)
// total = 42,205,184 floats = 168,820,736 bytes of d_ws.

#define NN 256
#define CDIM 128
#define NH 4
#define HD 32
#define NPOS (NN * NN)
#define LN_EPS 1e-5f

// ---------------------------------------------------------------- kernel A
// Fused LayerNorm + QKV/pair/gate projections. 16 positions per block.
__global__ __launch_bounds__(256) void k_proj(
    const float* __restrict__ z, const float* __restrict__ ln_g,
    const float* __restrict__ ln_b, const float* __restrict__ w_qkv,
    const float* __restrict__ w_pair, const float* __restrict__ w_gate,
    const float* __restrict__ b_gate, float* __restrict__ qkv,
    float* __restrict__ pb, float* __restrict__ gate)
{
    __shared__ float sZ[16][132];   // stride 132: 4-row groups hit distinct banks
    const int t = threadIdx.x;
    const int p0 = blockIdx.x * 16;

    // --- LayerNorm: 16 threads per row, 8 channels per thread
    {
        const int row = t >> 4;
        const int c0 = (t & 15) * 8;
        const float* zr = z + (size_t)(p0 + row) * CDIM + c0;
        float v[8];
        float s = 0.f, sq = 0.f;
#pragma unroll
        for (int u = 0; u < 8; ++u) { v[u] = zr[u]; s += v[u]; sq += v[u] * v[u]; }
#pragma unroll
        for (int m = 1; m < 16; m <<= 1) {
            s  += __shfl_xor(s,  m, 16);
            sq += __shfl_xor(sq, m, 16);
        }
        const float mu   = s * (1.f / CDIM);
        const float var  = sq * (1.f / CDIM) - mu * mu;
        const float rstd = rsqrtf(var + LN_EPS);
#pragma unroll
        for (int u = 0; u < 8; ++u) {
            const int c = c0 + u;
            sZ[row][c] = (v[u] - mu) * rstd * ln_g[c] + ln_b[c];
        }
    }
    __syncthreads();

    // --- projections: 516 outputs = 384 qkv + 4 pair + 128 gate
    const int ty = t >> 4, tx = t & 15;
    const size_t pos = (size_t)(p0 + ty);
    const float* zr = sZ[ty];
    for (int k = 0; k < 33; ++k) {
        const int o = tx + k * 16;
        if (o >= 516) break;               // no sync inside loop: safe divergence
        float acc = 0.f;
        if (o < 384) {
#pragma unroll 8
            for (int c = 0; c < CDIM; ++c) acc += zr[c] * w_qkv[c * 384 + o];
            qkv[pos * 384 + o] = acc;
        } else if (o < 388) {
            const int oo = o - 384;
#pragma unroll 8
            for (int c = 0; c < CDIM; ++c) acc += zr[c] * w_pair[c * 4 + oo];
            pb[pos * 4 + oo] = acc;
        } else {
            const int oo = o - 388;
#pragma unroll 8
            for (int c = 0; c < CDIM; ++c) acc += zr[c] * w_gate[c * 128 + oo];
            acc += b_gate[oo];
            gate[pos * 128 + oo] = 1.f / (1.f + __expf(-acc));
        }
    }
}

// ---------------------------------------------------------------- kernel B
// Row-wise attention. Block = (r, tile of 16 i). K/V for (r,h) staged in LDS.
__global__ __launch_bounds__(256) void k_attn(
    const float* __restrict__ qkv, const float* __restrict__ pbuf,
    const int* __restrict__ src_mask, float* __restrict__ ao)
{
    __shared__ float sK[256][33];
    __shared__ float sV[256][33];
    __shared__ float sQ[32];
    __shared__ float sP[256];
    __shared__ float sPart[8][33];
    __shared__ float sRedM[4], sRedS[4];
    __shared__ float sMf[256];

    const int t = threadIdx.x;
    const int itile = blockIdx.x;
    const int r = blockIdx.y;
    const int wid = t >> 6, lane = t & 63;
    const float scale = 0.17677669529663687f;  // 1/sqrt(32)

    sMf[t] = (src_mask[t] == 0) ? -1.f : 1.f;

    for (int h = 0; h < NH; ++h) {
        __syncthreads();   // previous use of sK/sV done (also publishes sMf)
        // load K,V rows for (r, all j, h): 8 passes, 8 threads per j-row
        {
            const int jj = t >> 3;
            const int q4 = (t & 7) * 4;
#pragma unroll
            for (int pp = 0; pp < 8; ++pp) {
                const int j = pp * 32 + jj;
                const float* kp = qkv + ((size_t)(r * 256 + j)) * 384 + 128 + h * 32 + q4;
                const float4 kv = *(const float4*)kp;
                const float4 vv = *(const float4*)(kp + 128);
                sK[j][q4 + 0] = kv.x; sK[j][q4 + 1] = kv.y;
                sK[j][q4 + 2] = kv.z; sK[j][q4 + 3] = kv.w;
                sV[j][q4 + 0] = vv.x; sV[j][q4 + 1] = vv.y;
                sV[j][q4 + 2] = vv.z; sV[j][q4 + 3] = vv.w;
            }
        }
        __syncthreads();

        for (int il = 0; il < 16; ++il) {
            const int i = itile * 16 + il;
            if (t < 32) sQ[t] = qkv[((size_t)(r * 256 + i)) * 384 + h * 32 + t];
            __syncthreads();

            // logits: thread t handles j = t
            float lg = 0.f;
#pragma unroll 8
            for (int d = 0; d < 32; ++d) lg += sQ[d] * sK[t][d];
            lg = lg * scale + pbuf[((size_t)i * 256 + t) * 4 + h];
            if (sMf[i] * sMf[t] < 0.f) lg = -1e-9f;   // faithful to torch: -1e-9, not -inf

            // softmax over 256 j
            float mx = lg;
#pragma unroll
            for (int m = 32; m; m >>= 1) mx = fmaxf(mx, __shfl_xor(mx, m, 64));
            if (lane == 0) sRedM[wid] = mx;
            __syncthreads();
            mx = fmaxf(fmaxf(sRedM[0], sRedM[1]), fmaxf(sRedM[2], sRedM[3]));
            const float e = __expf(lg - mx);
            sP[t] = e;
            float se = e;
#pragma unroll
            for (int m = 32; m; m >>= 1) se += __shfl_xor(se, m, 64);
            if (lane == 0) sRedS[wid] = se;
            __syncthreads();
            const float inv = 1.f / (sRedS[0] + sRedS[1] + sRedS[2] + sRedS[3]);

            // PV: thread (jg = t>>5, d = t&31) does a 32-j partial
            const int d = t & 31, jg = t >> 5;
            float acc = 0.f;
#pragma unroll 8
            for (int jj2 = 0; jj2 < 32; ++jj2) {
                const int j = jg * 32 + jj2;
                acc += sP[j] * sV[j][d];
            }
            sPart[jg][d] = acc;
            __syncthreads();
            if (t < 32) {
                float o = 0.f;
#pragma unroll
                for (int g = 0; g < 8; ++g) o += sPart[g][t];
                ao[((size_t)(r * 256 + i)) * 128 + h * 32 + t] = o * inv;
            }
            __syncthreads();
        }
    }
}

// ---------------------------------------------------------------- kernel C
// out = (gate * ao) @ w_out + b_out. 16 positions per block.
__global__ __launch_bounds__(256) void k_out(
    const float* __restrict__ gate, const float* __restrict__ ao,
    const float* __restrict__ w_out, const float* __restrict__ b_out,
    float* __restrict__ out)
{
    __shared__ float sX[16][132];
    const int t = threadIdx.x;
    const int p0 = blockIdx.x * 16;
    {
        const int row = t >> 4;
        const int c0 = (t & 15) * 8;
        const size_t base = (size_t)(p0 + row) * 128 + c0;
#pragma unroll
        for (int u = 0; u < 8; ++u)
            sX[row][c0 + u] = gate[base + u] * ao[base + u];
    }
    __syncthreads();
    const int ty = t >> 4, tx = t & 15;
    const size_t pos = (size_t)(p0 + ty);
#pragma unroll 1
    for (int k = 0; k < 8; ++k) {
        const int o = tx + k * 16;
        float acc = b_out[o];
#pragma unroll 8
        for (int c = 0; c < CDIM; ++c) acc += sX[ty][c] * w_out[c * 128 + o];
        out[pos * 128 + o] = acc;
    }
}

// ---------------------------------------------------------------- launch
extern "C" void kernel_launch(void* const* d_in, const int* in_sizes, int n_in,
                              void* d_out, int out_size, void* d_ws, size_t ws_size,
                              hipStream_t stream)
{
    const float* z      = (const float*)d_in[0];
    const int*   smask  = (const int*)d_in[1];
    const float* ln_g   = (const float*)d_in[2];
    const float* ln_b   = (const float*)d_in[3];
    const float* w_qkv  = (const float*)d_in[4];
    const float* w_pair = (const float*)d_in[5];
    const float* w_gate = (const float*)d_in[6];
    const float* b_gate = (const float*)d_in[7];
    const float* w_out  = (const float*)d_in[8];
    const float* b_out  = (const float*)d_in[9];
    float* out = (float*)d_out;

    float* ws   = (float*)d_ws;
    float* qkv  = ws;                               // 65536*384
    float* pb   = qkv + (size_t)NPOS * 384;         // 65536*4
    float* gate = pb + (size_t)NPOS * 4;            // 65536*128
    float* ao   = gate + (size_t)NPOS * 128;        // 65536*128

    k_proj<<<NPOS / 16, 256, 0, stream>>>(z, ln_g, ln_b, w_qkv, w_pair, w_gate,
                                          b_gate, qkv, pb, gate);
    k_attn<<<dim3(16, NN), 256, 0, stream>>>(qkv, pb, smask, ao);
    k_out<<<NPOS / 16, 256, 0, stream>>>(gate, ao, w_out, b_out, out);
}

// Round 2
// 134.541 us; speedup vs baseline: 12.2088x; 12.2088x over previous
//
#include <hip/hip_runtime.h>
#include <hip/hip_bf16.h>
#include <math.h>

// TriangleAttention MI355X round 2: bf16 MFMA pipeline.
// B=1, N=256, IN_DIM=128, H=4, D=32.
//
// ws layout (16B-aligned, 135.4 MB total):
//   znb  short[65536*128]      LN output, bf16, [p][c]
//   qkvb short[65536*384]      projections, bf16, [p][q0..127,k128..255,v256..383]
//   Vtb  short[4*256*32*256]   V transposed, [h][r][d][j]
//   wT   short[528*128]        all proj weights transposed [o][c] (0-383 qkv, 384-511 gate, 512-515 pair)
//   woT  short[128*128]        w_out transposed [o][c]
//   aob  short[65536*128]      gate * attn_out, bf16, [p][h*32+d]
//   pbf  float[4*65536]        pair bias [h][i*256+j]
//   gate float[65536*128]      sigmoid gate, f32

#define NPOS 65536
#define LN_EPS 1e-5f

typedef __attribute__((ext_vector_type(8))) short bf16x8;
typedef __attribute__((ext_vector_type(4))) float f32x4;

__device__ __forceinline__ short f2b(float f) {
    union { float f; unsigned u; } c; c.f = f;
    unsigned r = c.u + 0x7FFFu + ((c.u >> 16) & 1u);
    return (short)(r >> 16);
}

// ------------------------------------------------------------- weight prep
__global__ void k_prep(const float* __restrict__ wq, const float* __restrict__ wg,
                       const float* __restrict__ wp, const float* __restrict__ wo,
                       short* __restrict__ wT, short* __restrict__ woT)
{
    const int idx = blockIdx.x * 256 + threadIdx.x;
    const int stride = gridDim.x * 256;
    for (int i = idx; i < 528 * 128; i += stride) {
        const int o = i >> 7, c = i & 127;
        float v;
        if (o < 384)      v = wq[c * 384 + o];
        else if (o < 512) v = wg[c * 128 + (o - 384)];
        else if (o < 516) v = wp[c * 4 + (o - 512)];
        else              v = 0.f;
        wT[i] = f2b(v);
    }
    for (int i = idx; i < 128 * 128; i += stride) {
        const int o = i >> 7, c = i & 127;
        woT[i] = f2b(wo[c * 128 + o]);
    }
}

// ------------------------------------------------------------- layernorm
__global__ __launch_bounds__(256) void k_ln(const float* __restrict__ z,
                                            const float* __restrict__ g,
                                            const float* __restrict__ b,
                                            short* __restrict__ znb)
{
    const int t = threadIdx.x;
    const int row = blockIdx.x * 32 + (t >> 3);
    const int c0 = (t & 7) * 16;
    const float* zr = z + (size_t)row * 128 + c0;
    float v[16];
    float s = 0.f, sq = 0.f;
#pragma unroll
    for (int u = 0; u < 16; ++u) { v[u] = zr[u]; s += v[u]; sq += v[u] * v[u]; }
#pragma unroll
    for (int m = 1; m < 8; m <<= 1) {
        s  += __shfl_xor(s,  m, 8);
        sq += __shfl_xor(sq, m, 8);
    }
    const float mu = s * (1.f / 128.f);
    const float rstd = rsqrtf(sq * (1.f / 128.f) - mu * mu + LN_EPS);
    short tmp[16];
#pragma unroll
    for (int u = 0; u < 16; ++u)
        tmp[u] = f2b((v[u] - mu) * rstd * g[c0 + u] + b[c0 + u]);
    uint4* dst = (uint4*)(znb + (size_t)row * 128 + c0);
    dst[0] = *(uint4*)&tmp[0];
    dst[1] = *(uint4*)&tmp[8];
}

// ------------------------------------------------------------- projection GEMM
// [65536 x 128] @ [128 x 516] -> qkv(bf16) + Vt(bf16) + gate(f32,sigmoid) + pb(f32)
__global__ __launch_bounds__(256) void k_projmm(
    const short* __restrict__ znb, const short* __restrict__ wT,
    const float* __restrict__ b_gate, short* __restrict__ qkvb,
    short* __restrict__ Vtb, float* __restrict__ pbf, float* __restrict__ gate)
{
    const int t = threadIdx.x, w = t >> 6, l = t & 63;
    const int lg = l & 15, gr = l >> 4;
    const int p0 = blockIdx.x * 64;
    const f32x4 zero4 = {0.f, 0.f, 0.f, 0.f};

    bf16x8 a[4][4];
#pragma unroll
    for (int mt = 0; mt < 4; ++mt)
#pragma unroll
        for (int kc = 0; kc < 4; ++kc)
            a[mt][kc] = *(const bf16x8*)(znb + (size_t)(p0 + mt * 16 + lg) * 128 + kc * 32 + gr * 8);

    for (int nt = w; nt < 33; nt += 4) {
        bf16x8 bfr[4];
#pragma unroll
        for (int kc = 0; kc < 4; ++kc)
            bfr[kc] = *(const bf16x8*)(wT + (size_t)(nt * 16 + lg) * 128 + kc * 32 + gr * 8);
        const int o = nt * 16 + lg;
#pragma unroll
        for (int mt = 0; mt < 4; ++mt) {
            f32x4 acc = zero4;
#pragma unroll
            for (int kc = 0; kc < 4; ++kc)
                acc = __builtin_amdgcn_mfma_f32_16x16x32_bf16(a[mt][kc], bfr[kc], acc, 0, 0, 0);
            const int pr = p0 + mt * 16 + gr * 4;   // rows pr..pr+3
            if (o < 384) {
#pragma unroll
                for (int reg = 0; reg < 4; ++reg)
                    qkvb[(size_t)(pr + reg) * 384 + o] = f2b(acc[reg]);
                if (o >= 256) {
                    const int hh = (o - 256) >> 5, d = (o - 256) & 31;
                    const int r = pr >> 8, j = pr & 255;
                    const size_t base = (((size_t)hh * 256 + r) * 32 + d) * 256 + j;
#pragma unroll
                    for (int reg = 0; reg < 4; ++reg)
                        Vtb[base + reg] = f2b(acc[reg]);
                }
            } else if (o < 512) {
                const float bg = b_gate[o - 384];
#pragma unroll
                for (int reg = 0; reg < 4; ++reg)
                    gate[(size_t)(pr + reg) * 128 + (o - 384)] =
                        1.f / (1.f + __expf(-(acc[reg] + bg)));
            } else if (o < 516) {
                *(f32x4*)(pbf + (size_t)(o - 512) * NPOS + pr) = acc;
            }
        }
    }
}

// ------------------------------------------------------------- attention
// block = (r, i-half); wave = head. No __syncthreads (per-wave LDS only).
__global__ __launch_bounds__(256) void k_attn(
    const short* __restrict__ qkvb, const short* __restrict__ Vtb,
    const float* __restrict__ pbf, const int* __restrict__ smask,
    const float* __restrict__ gate, short* __restrict__ aob)
{
    __shared__ short sP[4][16 * 264];
    const int t = threadIdx.x, h = t >> 6, l = t & 63;
    const int lg = l & 15, gr = l >> 4;
    const int r = blockIdx.x >> 1, ihalf = blockIdx.x & 1;
    short* sPw = sP[h];
    const float scale = 0.17677669529663687f;  // 1/sqrt(32)
    const f32x4 zero4 = {0.f, 0.f, 0.f, 0.f};
    const size_t vbase = ((size_t)h * 256 + r) * 32 * 256;

    for (int mtl = 0; mtl < 8; ++mtl) {
        const int i0 = ihalf * 128 + mtl * 16;
        const bf16x8 qf = *(const bf16x8*)(qkvb + (size_t)(r * 256 + i0 + lg) * 384 + h * 32 + gr * 8);

        f32x4 accS[16];
#pragma unroll
        for (int nt = 0; nt < 16; ++nt) {
            const bf16x8 kf = *(const bf16x8*)(qkvb + (size_t)(r * 256 + nt * 16 + lg) * 384 + 128 + h * 32 + gr * 8);
            accS[nt] = __builtin_amdgcn_mfma_f32_16x16x32_bf16(qf, kf, zero4, 0, 0, 0);
        }

        int mi[4];
#pragma unroll
        for (int reg = 0; reg < 4; ++reg) mi[reg] = smask[i0 + gr * 4 + reg];

#pragma unroll
        for (int nt = 0; nt < 16; ++nt) {
            const int j = nt * 16 + lg;
            const int mj = smask[j];
#pragma unroll
            for (int reg = 0; reg < 4; ++reg) {
                const int i = i0 + gr * 4 + reg;
                float v = accS[nt][reg] * scale + pbf[(size_t)h * NPOS + i * 256 + j];
                if ((mi[reg] == 0) != (mj == 0)) v = -1e-9f;   // torch-faithful
                accS[nt][reg] = v;
            }
        }

        float inv[4];
#pragma unroll
        for (int reg = 0; reg < 4; ++reg) {
            float m = accS[0][reg];
#pragma unroll
            for (int nt = 1; nt < 16; ++nt) m = fmaxf(m, accS[nt][reg]);
#pragma unroll
            for (int msk = 1; msk < 16; msk <<= 1) m = fmaxf(m, __shfl_xor(m, msk, 16));
            float s = 0.f;
#pragma unroll
            for (int nt = 0; nt < 16; ++nt) {
                const float e = __expf(accS[nt][reg] - m);
                accS[nt][reg] = e;
                s += e;
            }
#pragma unroll
            for (int msk = 1; msk < 16; msk <<= 1) s += __shfl_xor(s, msk, 16);
            inv[reg] = 1.f / s;
        }

        // P -> LDS (C-layout rows -> A-frag layout), bf16
#pragma unroll
        for (int nt = 0; nt < 16; ++nt)
#pragma unroll
            for (int reg = 0; reg < 4; ++reg)
                sPw[(gr * 4 + reg) * 264 + nt * 16 + lg] = f2b(accS[nt][reg]);

        // PV: A = P[16 x 256] from LDS, B = Vt[h][r][d][j]
        f32x4 o0 = zero4, o1 = zero4;
#pragma unroll
        for (int kc = 0; kc < 8; ++kc) {
            const bf16x8 pa = *(const bf16x8*)(sPw + lg * 264 + kc * 32 + gr * 8);
            const bf16x8 v0 = *(const bf16x8*)(Vtb + vbase + (size_t)lg * 256 + kc * 32 + gr * 8);
            const bf16x8 v1 = *(const bf16x8*)(Vtb + vbase + (size_t)(16 + lg) * 256 + kc * 32 + gr * 8);
            o0 = __builtin_amdgcn_mfma_f32_16x16x32_bf16(pa, v0, o0, 0, 0, 0);
            o1 = __builtin_amdgcn_mfma_f32_16x16x32_bf16(pa, v1, o1, 0, 0, 0);
        }

        // epilogue: normalize, gate, store bf16
#pragma unroll
        for (int reg = 0; reg < 4; ++reg) {
            const size_t p = (size_t)r * 256 + i0 + gr * 4 + reg;
            const float g0 = gate[p * 128 + h * 32 + lg];
            const float g1 = gate[p * 128 + h * 32 + 16 + lg];
            aob[p * 128 + h * 32 + lg]      = f2b(o0[reg] * inv[reg] * g0);
            aob[p * 128 + h * 32 + 16 + lg] = f2b(o1[reg] * inv[reg] * g1);
        }
    }
}

// ------------------------------------------------------------- out projection
__global__ __launch_bounds__(256) void k_outmm(
    const short* __restrict__ aob, const short* __restrict__ woT,
    const float* __restrict__ b_out, float* __restrict__ out)
{
    const int t = threadIdx.x, w = t >> 6, l = t & 63;
    const int lg = l & 15, gr = l >> 4;
    const int p0 = blockIdx.x * 64;
    const f32x4 zero4 = {0.f, 0.f, 0.f, 0.f};

    bf16x8 a[4][4];
#pragma unroll
    for (int mt = 0; mt < 4; ++mt)
#pragma unroll
        for (int kc = 0; kc < 4; ++kc)
            a[mt][kc] = *(const bf16x8*)(aob + (size_t)(p0 + mt * 16 + lg) * 128 + kc * 32 + gr * 8);

    for (int nt = w; nt < 8; nt += 4) {
        bf16x8 bfr[4];
#pragma unroll
        for (int kc = 0; kc < 4; ++kc)
            bfr[kc] = *(const bf16x8*)(woT + (size_t)(nt * 16 + lg) * 128 + kc * 32 + gr * 8);
        const int o = nt * 16 + lg;
        const float bo = b_out[o];
#pragma unroll
        for (int mt = 0; mt < 4; ++mt) {
            f32x4 acc = zero4;
#pragma unroll
            for (int kc = 0; kc < 4; ++kc)
                acc = __builtin_amdgcn_mfma_f32_16x16x32_bf16(a[mt][kc], bfr[kc], acc, 0, 0, 0);
#pragma unroll
            for (int reg = 0; reg < 4; ++reg)
                out[(size_t)(p0 + mt * 16 + gr * 4 + reg) * 128 + o] = acc[reg] + bo;
        }
    }
}

// ------------------------------------------------------------- launch
extern "C" void kernel_launch(void* const* d_in, const int* in_sizes, int n_in,
                              void* d_out, int out_size, void* d_ws, size_t ws_size,
                              hipStream_t stream)
{
    const float* z      = (const float*)d_in[0];
    const int*   smask  = (const int*)d_in[1];
    const float* ln_g   = (const float*)d_in[2];
    const float* ln_b   = (const float*)d_in[3];
    const float* w_qkv  = (const float*)d_in[4];
    const float* w_pair = (const float*)d_in[5];
    const float* w_gate = (const float*)d_in[6];
    const float* b_gate = (const float*)d_in[7];
    const float* w_out  = (const float*)d_in[8];
    const float* b_out  = (const float*)d_in[9];
    float* out = (float*)d_out;

    short* ws   = (short*)d_ws;
    short* znb  = ws;                                  // 65536*128
    short* qkvb = znb + (size_t)NPOS * 128;            // 65536*384
    short* Vtb  = qkvb + (size_t)NPOS * 384;           // 4*256*32*256 = 8388608
    short* wT   = Vtb + (size_t)8388608;               // 528*128
    short* woT  = wT + 528 * 128;                      // 128*128
    short* aob  = woT + 128 * 128;                     // 65536*128
    float* pbf  = (float*)(aob + (size_t)NPOS * 128);  // 4*65536
    float* gate = pbf + (size_t)4 * NPOS;              // 65536*128

    k_prep<<<64, 256, 0, stream>>>(w_qkv, w_gate, w_pair, w_out, wT, woT);
    k_ln<<<NPOS / 32, 256, 0, stream>>>(z, ln_g, ln_b, znb);
    k_projmm<<<NPOS / 64, 256, 0, stream>>>(znb, wT, b_gate, qkvb, Vtb, pbf, gate);
    k_attn<<<512, 256, 0, stream>>>(qkvb, Vtb, pbf, smask, gate, aob);
    k_outmm<<<NPOS / 64, 256, 0, stream>>>(aob, woT, b_out, out);
}

// Round 3
// 132.579 us; speedup vs baseline: 12.3895x; 1.0148x over previous
//
#include <hip/hip_runtime.h>
#include <hip/hip_bf16.h>
#include <math.h>

// TriangleAttention MI355X round 3.
// B=1, N=256, IN_DIM=128, H=4, D=32.
// 3 kernels: k_prep (weights->bf16), k_proj (LN + qkv/pair/gate GEMM),
// k_attn (attention + gate + out-projection, fused).
//
// ws layout:
//   qkb  short[65536*256]      [p][q0..127 | k128..255]  bf16
//   Vtb  short[4*256*32*256]   [h][r][d][j]              bf16
//   wT   short[528*128]        proj weights [o][c] (0-383 qkv, 384-511 gate, 512-515 pair)
//   woT  short[128*128]        w_out [o][c]
//   pbf  float[4*65536]        pair bias [h][i*256+j]
//   gate float[65536*128]      sigmoid gate

#define NPOS 65536
#define LN_EPS 1e-5f

typedef __attribute__((ext_vector_type(8))) short bf16x8;
typedef __attribute__((ext_vector_type(4))) float f32x4;

__device__ __forceinline__ short f2b(float f) {
    union { float f; unsigned u; } c; c.f = f;
    unsigned r = c.u + 0x7FFFu + ((c.u >> 16) & 1u);
    return (short)(r >> 16);
}

// ------------------------------------------------------------- weight prep
__global__ void k_prep(const float* __restrict__ wq, const float* __restrict__ wg,
                       const float* __restrict__ wp, const float* __restrict__ wo,
                       short* __restrict__ wT, short* __restrict__ woT)
{
    const int idx = blockIdx.x * 256 + threadIdx.x;
    const int stride = gridDim.x * 256;
    for (int i = idx; i < 528 * 128; i += stride) {
        const int o = i >> 7, c = i & 127;
        float v;
        if (o < 384)      v = wq[c * 384 + o];
        else if (o < 512) v = wg[c * 128 + (o - 384)];
        else if (o < 516) v = wp[c * 4 + (o - 512)];
        else              v = 0.f;
        wT[i] = f2b(v);
    }
    for (int i = idx; i < 128 * 128; i += stride) {
        const int o = i >> 7, c = i & 127;
        woT[i] = f2b(wo[c * 128 + o]);
    }
}

// ------------------------------------------------------------- LN + projections
// 64 positions per block. LN in-kernel -> LDS bf16 -> MFMA GEMM, K=128.
__global__ __launch_bounds__(256) void k_proj(
    const float* __restrict__ z, const float* __restrict__ ln_g,
    const float* __restrict__ ln_b, const short* __restrict__ wT,
    const float* __restrict__ b_gate, short* __restrict__ qkb,
    short* __restrict__ Vtb, float* __restrict__ pbf, float* __restrict__ gate)
{
    __shared__ short sZn[64 * 136];   // stride 136 shorts = 17 x 16B units: conflict-free frag reads
    const int t = threadIdx.x, w = t >> 6, l = t & 63;
    const int lg = l & 15, gr = l >> 4;
    const int p0 = blockIdx.x * 64;
    const f32x4 zero4 = {0.f, 0.f, 0.f, 0.f};

    // --- LayerNorm: 4 threads per row, 32 channels each
    {
        const int row = t >> 2, q = t & 3;
        const float* zr = z + (size_t)(p0 + row) * 128 + q * 32;
        float v[32];
        float s = 0.f, sq = 0.f;
#pragma unroll
        for (int u = 0; u < 8; ++u) {
            const float4 f = ((const float4*)zr)[u];
            v[u * 4 + 0] = f.x; v[u * 4 + 1] = f.y;
            v[u * 4 + 2] = f.z; v[u * 4 + 3] = f.w;
            s += f.x + f.y + f.z + f.w;
            sq += f.x * f.x + f.y * f.y + f.z * f.z + f.w * f.w;
        }
        s  += __shfl_xor(s, 1, 4);  s  += __shfl_xor(s, 2, 4);
        sq += __shfl_xor(sq, 1, 4); sq += __shfl_xor(sq, 2, 4);
        const float mu = s * (1.f / 128.f);
        const float rstd = rsqrtf(sq * (1.f / 128.f) - mu * mu + LN_EPS);
        short tmp[32];
#pragma unroll
        for (int u = 0; u < 32; ++u) {
            const int c = q * 32 + u;
            tmp[u] = f2b((v[u] - mu) * rstd * ln_g[c] + ln_b[c]);
        }
        uint4* dst = (uint4*)(sZn + row * 136 + q * 32);
#pragma unroll
        for (int u = 0; u < 4; ++u) dst[u] = *(uint4*)&tmp[u * 8];
    }
    __syncthreads();

    // --- A-fragments for 64 rows
    bf16x8 a[4][4];
#pragma unroll
    for (int mt = 0; mt < 4; ++mt)
#pragma unroll
        for (int kc = 0; kc < 4; ++kc)
            a[mt][kc] = *(const bf16x8*)(sZn + (mt * 16 + lg) * 136 + kc * 32 + gr * 8);

    for (int nt = w; nt < 33; nt += 4) {
        bf16x8 bfr[4];
#pragma unroll
        for (int kc = 0; kc < 4; ++kc)
            bfr[kc] = *(const bf16x8*)(wT + (size_t)(nt * 16 + lg) * 128 + kc * 32 + gr * 8);
        const int o = nt * 16 + lg;
#pragma unroll
        for (int mt = 0; mt < 4; ++mt) {
            f32x4 acc = zero4;
#pragma unroll
            for (int kc = 0; kc < 4; ++kc)
                acc = __builtin_amdgcn_mfma_f32_16x16x32_bf16(a[mt][kc], bfr[kc], acc, 0, 0, 0);
            const int pr = p0 + mt * 16 + gr * 4;   // rows pr..pr+3
            if (o < 256) {
#pragma unroll
                for (int reg = 0; reg < 4; ++reg)
                    qkb[(size_t)(pr + reg) * 256 + o] = f2b(acc[reg]);
            } else if (o < 384) {
                const int hh = (o - 256) >> 5, d = (o - 256) & 31;
                const int r = pr >> 8, j = pr & 255;
                union { unsigned long long u; short sh[4]; } pk;
#pragma unroll
                for (int reg = 0; reg < 4; ++reg) pk.sh[reg] = f2b(acc[reg]);
                *(unsigned long long*)(Vtb + (((size_t)hh * 256 + r) * 32 + d) * 256 + j) = pk.u;
            } else if (o < 512) {
                const float bg = b_gate[o - 384];
#pragma unroll
                for (int reg = 0; reg < 4; ++reg)
                    gate[(size_t)(pr + reg) * 128 + (o - 384)] =
                        1.f / (1.f + __expf(-(acc[reg] + bg)));
            } else if (o < 516) {
                *(f32x4*)(pbf + (size_t)(o - 512) * NPOS + pr) = acc;
            }
        }
    }
}

// ------------------------------------------------------------- attention + out-proj
// block = (r, ihalf of 128 i); wave = head. Swapped QK^T: lane holds P[j0..j0+3][i=lg].
// P buffer: per-wave, row=i (16 rows x 512B), 16B-unit rotation by row -> conflict-free.
__global__ __launch_bounds__(256, 2) void k_attn(
    const short* __restrict__ qkb, const short* __restrict__ Vtb,
    const float* __restrict__ pbf, const int* __restrict__ smask,
    const float* __restrict__ gate, const short* __restrict__ woT,
    const float* __restrict__ b_out, float* __restrict__ out)
{
    __shared__ short sP[4 * 4096];    // 4 waves x 16 rows x 256 shorts (rotated units)
    __shared__ short sX[128 * 136];   // gated attention output, bf16
    __shared__ float sMf[256];

    const int t = threadIdx.x, h = t >> 6, l = t & 63;
    const int lg = l & 15, gr = l >> 4;
    const int r = blockIdx.x >> 1, ihalf = blockIdx.x & 1;
    char* sPw = (char*)(sP + h * 4096);
    const float scale = 0.17677669529663687f;  // 1/sqrt(32)
    const f32x4 zero4 = {0.f, 0.f, 0.f, 0.f};
    const size_t vbase = ((size_t)h * 256 + r) * 8192;

    sMf[t] = (smask[t] == 0) ? -1.f : 1.f;
    __syncthreads();

    // per-lane mask bits for this lane's j set: j = nt*16 + gr*4 + reg
    unsigned long long mjb = 0;
#pragma unroll
    for (int nt = 0; nt < 16; ++nt)
#pragma unroll
        for (int reg = 0; reg < 4; ++reg)
            if (sMf[nt * 16 + gr * 4 + reg] < 0.f)
                mjb |= 1ull << (nt * 4 + reg);

    // hoist K fragments for the whole row r (head h): 64 VGPRs
    bf16x8 kf[16];
#pragma unroll
    for (int nt = 0; nt < 16; ++nt)
        kf[nt] = *(const bf16x8*)(qkb + (size_t)(r * 256 + nt * 16 + lg) * 256 + 128 + h * 32 + gr * 8);

    for (int mtl = 0; mtl < 8; ++mtl) {
        const int i0 = ihalf * 128 + mtl * 16;
        const bf16x8 qf = *(const bf16x8*)(qkb + (size_t)(r * 256 + i0 + lg) * 256 + h * 32 + gr * 8);

        f32x4 accS[16];
#pragma unroll
        for (int nt = 0; nt < 16; ++nt)
            accS[nt] = __builtin_amdgcn_mfma_f32_16x16x32_bf16(kf[nt], qf, zero4, 0, 0, 0);

        const bool bi = sMf[i0 + lg] < 0.f;
#pragma unroll
        for (int nt = 0; nt < 16; ++nt) {
            const f32x4 pbv = *(const f32x4*)(pbf + (size_t)h * NPOS + (size_t)(i0 + lg) * 256 + nt * 16 + gr * 4);
#pragma unroll
            for (int reg = 0; reg < 4; ++reg) {
                const bool bj = (mjb >> (nt * 4 + reg)) & 1;
                float v = accS[nt][reg] * scale + pbv[reg];
                accS[nt][reg] = (bi != bj) ? -1e-9f : v;
            }
        }

        // softmax over j (in-lane 64 values + cross-gr shuffles)
        float m = -3.4e38f;
#pragma unroll
        for (int nt = 0; nt < 16; ++nt)
#pragma unroll
            for (int reg = 0; reg < 4; ++reg) m = fmaxf(m, accS[nt][reg]);
        m = fmaxf(m, __shfl_xor(m, 16));
        m = fmaxf(m, __shfl_xor(m, 32));
        float s = 0.f;
#pragma unroll
        for (int nt = 0; nt < 16; ++nt)
#pragma unroll
            for (int reg = 0; reg < 4; ++reg) {
                const float e = __expf(accS[nt][reg] - m);
                accS[nt][reg] = e;
                s += e;
            }
        s += __shfl_xor(s, 16);
        s += __shfl_xor(s, 32);
        const float inv = 1.f / s;   // for i = lg

        // pack P -> per-wave LDS (row = i = lg, rotated 16B units)
#pragma unroll
        for (int nt = 0; nt < 16; ++nt) {
            union { unsigned long long u; short sh[4]; } pk;
#pragma unroll
            for (int reg = 0; reg < 4; ++reg) pk.sh[reg] = f2b(accS[nt][reg]);
            const int unit = (nt * 2 + (gr >> 1) + lg) & 31;
            *(unsigned long long*)(sPw + lg * 512 + unit * 16 + (gr & 1) * 8) = pk.u;
        }

        // PV: A = P[i][j] from LDS, B = Vt[d][j]
        f32x4 o0 = zero4, o1 = zero4;
#pragma unroll
        for (int kc = 0; kc < 8; ++kc) {
            const int unit = (kc * 4 + gr + lg) & 31;
            const bf16x8 pa = *(const bf16x8*)(sPw + lg * 512 + unit * 16);
            const bf16x8 v0 = *(const bf16x8*)(Vtb + vbase + (size_t)lg * 256 + kc * 32 + gr * 8);
            const bf16x8 v1 = *(const bf16x8*)(Vtb + vbase + (size_t)(lg + 16) * 256 + kc * 32 + gr * 8);
            o0 = __builtin_amdgcn_mfma_f32_16x16x32_bf16(pa, v0, o0, 0, 0, 0);
            o1 = __builtin_amdgcn_mfma_f32_16x16x32_bf16(pa, v1, o1, 0, 0, 0);
        }

        // epilogue: normalize (inv from lane lg == i), gate, stash bf16 in sX
#pragma unroll
        for (int reg = 0; reg < 4; ++reg) {
            const float invr = __shfl(inv, gr * 4 + reg, 16);
            const int il = mtl * 16 + gr * 4 + reg;
            const size_t p = (size_t)r * 256 + ihalf * 128 + il;
            const float g0 = gate[p * 128 + h * 32 + lg];
            const float g1 = gate[p * 128 + h * 32 + 16 + lg];
            sX[il * 136 + h * 32 + lg]      = f2b(o0[reg] * invr * g0);
            sX[il * 136 + h * 32 + 16 + lg] = f2b(o1[reg] * invr * g1);
        }
    }
    __syncthreads();

    // --- out-projection: wave h handles rows h*32 .. h*32+31
    bf16x8 a0[4], a1[4];
#pragma unroll
    for (int kc = 0; kc < 4; ++kc) {
        a0[kc] = *(const bf16x8*)(sX + (h * 32 + lg) * 136 + kc * 32 + gr * 8);
        a1[kc] = *(const bf16x8*)(sX + (h * 32 + 16 + lg) * 136 + kc * 32 + gr * 8);
    }
    const size_t prow = (size_t)r * 256 + ihalf * 128 + h * 32;
    for (int nt = 0; nt < 8; ++nt) {
        bf16x8 bfr[4];
#pragma unroll
        for (int kc = 0; kc < 4; ++kc)
            bfr[kc] = *(const bf16x8*)(woT + (size_t)(nt * 16 + lg) * 128 + kc * 32 + gr * 8);
        f32x4 c0 = zero4, c1 = zero4;
#pragma unroll
        for (int kc = 0; kc < 4; ++kc) {
            c0 = __builtin_amdgcn_mfma_f32_16x16x32_bf16(a0[kc], bfr[kc], c0, 0, 0, 0);
            c1 = __builtin_amdgcn_mfma_f32_16x16x32_bf16(a1[kc], bfr[kc], c1, 0, 0, 0);
        }
        const int o = nt * 16 + lg;
        const float bo = b_out[o];
#pragma unroll
        for (int reg = 0; reg < 4; ++reg) {
            out[(prow + gr * 4 + reg) * 128 + o]      = c0[reg] + bo;
            out[(prow + 16 + gr * 4 + reg) * 128 + o] = c1[reg] + bo;
        }
    }
}

// ------------------------------------------------------------- launch
extern "C" void kernel_launch(void* const* d_in, const int* in_sizes, int n_in,
                              void* d_out, int out_size, void* d_ws, size_t ws_size,
                              hipStream_t stream)
{
    const float* z      = (const float*)d_in[0];
    const int*   smask  = (const int*)d_in[1];
    const float* ln_g   = (const float*)d_in[2];
    const float* ln_b   = (const float*)d_in[3];
    const float* w_qkv  = (const float*)d_in[4];
    const float* w_pair = (const float*)d_in[5];
    const float* w_gate = (const float*)d_in[6];
    const float* b_gate = (const float*)d_in[7];
    const float* w_out  = (const float*)d_in[8];
    const float* b_out  = (const float*)d_in[9];
    float* out = (float*)d_out;

    short* ws   = (short*)d_ws;
    short* qkb  = ws;                                  // 65536*256
    short* Vtb  = qkb + (size_t)NPOS * 256;            // 8388608
    short* wT   = Vtb + (size_t)8388608;               // 528*128
    short* woT  = wT + 528 * 128;                      // 128*128
    float* pbf  = (float*)(woT + 128 * 128);           // 4*65536
    float* gate = pbf + (size_t)4 * NPOS;              // 65536*128

    k_prep<<<64, 256, 0, stream>>>(w_qkv, w_gate, w_pair, w_out, wT, woT);
    k_proj<<<NPOS / 64, 256, 0, stream>>>(z, ln_g, ln_b, wT, b_gate, qkb, Vtb, pbf, gate);
    k_attn<<<512, 256, 0, stream>>>(qkb, Vtb, pbf, smask, gate, woT, b_out, out);
}